// Round 15
// baseline (267.310 us; speedup 1.0000x reference)
//
#include <hip/hip_runtime.h>
#include <math.h>

#define NP 512
#define TS 128
#define GI 33
#define TAB2D (GI * GI)     // 1089
#define GV 257              // V-table nodes per timestep, h = 1/256
#define V_Lc 3.4f
#define V_0c 4.2f
#define GAMMAc 0.9f
#define ALPHAc 0.15f
#define BETAc 15.0f
#define E_INV 2e-5f
#define F_STDc 0.05f
#define G_STDc 0.02f

// light barrier: LDS-ordering only, leaves global loads/stores in flight
#define LBAR() asm volatile("s_waitcnt lgkmcnt(0)\n\ts_barrier" ::: "memory")

__device__ __forceinline__ float sigmoid_jax(float x) {
    float e = expf(-fabsf(x));
    float num = (x >= 0.f) ? 1.f : e;
    return num / (1.f + e);
}

__device__ __forceinline__ float vocf(float s) {
    float sm1 = s - 1.f;
    return V_Lc + (V_0c - V_Lc) * expf(GAMMAc * sm1)
         + (ALPHAc * V_Lc) * sm1
         + (1.f - ALPHAc) * V_Lc * (expf(-BETAc) - expf(-BETAc * sqrtf(s)));
}

// ---------------- DPP cross-lane helpers --------------------------------
template <int R>
__device__ __forceinline__ int dpp_ror(int v) {
    return __builtin_amdgcn_update_dpp(0, v, 0x120 | R, 0xf, 0xf, false);
}
template <int S>
__device__ __forceinline__ int dpp_shr(int v) {
    return __builtin_amdgcn_update_dpp(0, v, 0x110 | S, 0xf, 0xf, true);
}
__device__ __forceinline__ float rdlane_f(float v, int l) {
    return __int_as_float(__builtin_amdgcn_readlane(__float_as_int(v), l));
}

__device__ __forceinline__ float wave_max_f(float v) {
    v = fmaxf(v, __int_as_float(dpp_ror<1>(__float_as_int(v))));
    v = fmaxf(v, __int_as_float(dpp_ror<2>(__float_as_int(v))));
    v = fmaxf(v, __int_as_float(dpp_ror<4>(__float_as_int(v))));
    v = fmaxf(v, __int_as_float(dpp_ror<8>(__float_as_int(v))));
    int iv = __float_as_int(v);
    v = fmaxf(v, __int_as_float(__builtin_amdgcn_update_dpp(iv, iv, 0x142, 0xf, 0xf, false))); // bcast15
    iv = __float_as_int(v);
    v = fmaxf(v, __int_as_float(__builtin_amdgcn_update_dpp(iv, iv, 0x143, 0xf, 0xf, false))); // bcast31
    return rdlane_f(v, 63);
}

__device__ __forceinline__ int wave_max_i(int v) {
    v = max(v, dpp_ror<1>(v));
    v = max(v, dpp_ror<2>(v));
    v = max(v, dpp_ror<4>(v));
    v = max(v, dpp_ror<8>(v));
    v = max(v, __builtin_amdgcn_update_dpp(v, v, 0x142, 0xf, 0xf, false));
    v = max(v, __builtin_amdgcn_update_dpp(v, v, 0x143, 0xf, 0xf, false));
    return __builtin_amdgcn_readlane(v, 63);
}

__device__ __forceinline__ float wave_scan_add(float v, int lane) {
    v += __int_as_float(dpp_shr<1>(__float_as_int(v)));
    v += __int_as_float(dpp_shr<2>(__float_as_int(v)));
    v += __int_as_float(dpp_shr<4>(__float_as_int(v)));
    v += __int_as_float(dpp_shr<8>(__float_as_int(v)));
    float s15 = rdlane_f(v, 15);
    float s31 = rdlane_f(v, 31);
    float s47 = rdlane_f(v, 47);
    int row = lane >> 4;
    if (row >= 1) v += s15;
    if (row >= 2) v += s31;
    if (row >= 3) v += s47;
    return v;
}

__device__ __forceinline__ int wave_scanmax_i(int v, int lane) {
    v = max(v, dpp_shr<1>(v));
    v = max(v, dpp_shr<2>(v));
    v = max(v, dpp_shr<4>(v));
    v = max(v, dpp_shr<8>(v));
    int r15 = __builtin_amdgcn_readlane(v, 15);
    int r31 = __builtin_amdgcn_readlane(v, 31);
    int r47 = __builtin_amdgcn_readlane(v, 47);
    int row = lane >> 4;
    if (row >= 1) v = max(v, r15);
    if (row >= 2) v = max(v, r31);
    if (row >= 3) v = max(v, r47);
    return v;
}

// cubic Lagrange on a 33-node row at value s in [0,1] (h = 1/32)
__device__ __forceinline__ float interp33(const float* __restrict__ row, float s) {
    float x = s * 32.0f;
    int j = (int)floorf(x);
    j = j < 0 ? 0 : (j > 31 ? 31 : j);
    int st = j - 1;
    st = st < 0 ? 0 : (st > 29 ? 29 : st);
    float uu = x - (float)st;
    float um0 = uu, um1 = uu - 1.f, um2 = uu - 2.f, um3 = uu - 3.f;
    float c0 = um1 * um2 * um3 * (-1.f / 6.f);
    float c1 = um0 * um2 * um3 * (0.5f);
    float c2 = um0 * um1 * um3 * (-0.5f);
    float c3 = um0 * um1 * um2 * (1.f / 6.f);
    return c0 * row[st] + c1 * row[st + 1] + c2 * row[st + 2] + c3 * row[st + 3];
}

// cubic Lagrange on a 257-node row at x = s*256 (clamped)
__device__ __forceinline__ float interp257(const float* __restrict__ row, float s) {
    float x = s * 256.0f;
    int j = (int)floorf(x);
    j = j < 0 ? 0 : (j > 255 ? 255 : j);
    int st = j - 1;
    st = st < 0 ? 0 : (st > 253 ? 253 : st);
    float uu = x - (float)st;
    float um0 = uu, um1 = uu - 1.f, um2 = uu - 2.f, um3 = uu - 3.f;
    float c0 = um1 * um2 * um3 * (-1.f / 6.f);
    float c1 = um0 * um2 * um3 * (0.5f);
    float c2 = um0 * um1 * um3 * (-0.5f);
    float c3 = um0 * um1 * um2 * (1.f / 6.f);
    return c0 * row[st] + c1 * row[st + 1] + c2 * row[st + 2] + c3 * row[st + 3];
}

// count of slots i in [0,512) with fl(i+u) <= C (+-1 fixup)
__device__ __forceinline__ int count_le(float C, float u) {
    int h = (int)floorf(C - u);
    h = h < -1 ? -1 : (h > 511 ? 511 : h);
    h += (int)((h < 511) && (((float)(h + 1) + u) <= C));
    h -= (int)((h >= 0) && (((float)h + u) > C));
    return h + 1;
}

// ---------------------------------------------------------------------------
// Phase A: 2-D table Z(s_i, I_j) on 33x33 nodes, partial dots per 256-col half.
// Grid: 138 blocks = 69 rowblocks (16 rows) x 2 colhalves. 2 rows/thread.
// (verbatim R13/R14)
// ---------------------------------------------------------------------------
#define BKT 32
__global__ __launch_bounds__(256) void k_tab(
    const float* __restrict__ w1, const float* __restrict__ b1,
    const float* __restrict__ w2, const float* __restrict__ b2,
    const float* __restrict__ w3, float* __restrict__ zpart)
{
    const int tid = threadIdx.x;
    const int rowblk = blockIdx.x >> 1;
    const int colhalf = blockIdx.x & 1;
    const int r0 = rowblk * 16;
    const int cbase = colhalf * 256;

    __shared__ float As[16][BKT + 1];
    __shared__ float Bs[BKT][256];
    __shared__ float srow[16], irow[16];

    if (tid < 16) {
        int r = r0 + tid;
        r = r > (TAB2D - 1) ? (TAB2D - 1) : r;
        int si = r / GI;
        int ii = r - si * GI;
        srow[tid] = (float)si * (1.0f / 32.0f);
        irow[tid] = (float)ii * (1.0f / 32.0f);
    }
    __syncthreads();

    const int rg = tid >> 5;
    const int ct = tid & 31;
    float acc[2][8];
    #pragma unroll
    for (int a = 0; a < 2; ++a)
        #pragma unroll
        for (int b = 0; b < 8; ++b) acc[a][b] = 0.f;

    for (int kk = 0; kk < 1024; kk += BKT) {
        #pragma unroll
        for (int h = 0; h < 2; ++h) {
            int idx = tid + h * 256;
            int row = idx >> 5, k = idx & 31, kc = kk + k;
            float pre = srow[row] * w1[kc] + irow[row] * w1[1024 + kc] + b1[kc];
            As[row][k] = sigmoid_jax(pre);
        }
        #pragma unroll
        for (int jj = 0; jj < 8; ++jj) {
            int vi = tid + jj * 256;
            int k = vi >> 6, c4 = vi & 63;
            *(float4*)&Bs[k][c4 * 4] = *(const float4*)&w2[(kk + k) * 512 + cbase + c4 * 4];
        }
        __syncthreads();
        #pragma unroll
        for (int k = 0; k < BKT; ++k) {
            float a0 = As[rg * 2][k];
            float a1 = As[rg * 2 + 1][k];
            float bq[8];
            *(float4*)&bq[0] = *(const float4*)&Bs[k][ct * 4];
            *(float4*)&bq[4] = *(const float4*)&Bs[k][ct * 4 + 128];
            #pragma unroll
            for (int q = 0; q < 8; ++q) {
                acc[0][q] += a0 * bq[q];
                acc[1][q] += a1 * bq[q];
            }
        }
        __syncthreads();
    }

    float b2r[8], w3r[8];
    *(float4*)&b2r[0] = *(const float4*)&b2[cbase + ct * 4];
    *(float4*)&b2r[4] = *(const float4*)&b2[cbase + ct * 4 + 128];
    *(float4*)&w3r[0] = *(const float4*)&w3[cbase + ct * 4];
    *(float4*)&w3r[4] = *(const float4*)&w3[cbase + ct * 4 + 128];
    #pragma unroll
    for (int rr = 0; rr < 2; ++rr) {
        float zp = 0.f;
        #pragma unroll
        for (int q = 0; q < 8; ++q)
            zp += w3r[q] * sigmoid_jax(acc[rr][q] + b2r[q]);
        #pragma unroll
        for (int mm = 1; mm < 32; mm <<= 1) zp += __shfl_xor(zp, mm);
        if (ct == 0 && (r0 + rg * 2 + rr) < TAB2D)
            zpart[colhalf * TAB2D + r0 + rg * 2 + rr] = zp;
    }
}

// ---------------------------------------------------------------------------
// Phase A2: build vt[t][257] tables in parallel (128 blocks, one per t).
// zrow formula bit-identical to R14's k_pre.
// ---------------------------------------------------------------------------
__global__ __launch_bounds__(320) void k_pre(
    const float* __restrict__ zpart, const float* __restrict__ current,
    const float* __restrict__ b3, float* __restrict__ vt_g)
{
    __shared__ float zrow[GI];
    const int t = blockIdx.x;
    const int tid = threadIdx.x;
    const float It = current[t];
    const float bb3 = b3[0];

    if (tid < GI) {
        float x = It * 32.0f;
        int j = (int)floorf(x);
        j = j < 0 ? 0 : (j > 31 ? 31 : j);
        int st = j - 1;
        st = st < 0 ? 0 : (st > 29 ? 29 : st);
        float uu = x - (float)st;
        float um0 = uu, um1 = uu - 1.f, um2 = uu - 2.f, um3 = uu - 3.f;
        float c0 = um1 * um2 * um3 * (-1.f / 6.f);
        float c1 = um0 * um2 * um3 * (0.5f);
        float c2 = um0 * um1 * um3 * (-0.5f);
        float c3 = um0 * um1 * um2 * (1.f / 6.f);
        int base = tid * GI + st;
        float n0 = zpart[base]     + zpart[TAB2D + base]     + bb3;
        float n1 = zpart[base + 1] + zpart[TAB2D + base + 1] + bb3;
        float n2 = zpart[base + 2] + zpart[TAB2D + base + 2] + bb3;
        float n3 = zpart[base + 3] + zpart[TAB2D + base + 3] + bb3;
        zrow[tid] = c0 * n0 + c1 * n1 + c2 * n2 + c3 * n3;
    }
    __syncthreads();
    if (tid < GV) {
        float sj = (float)tid * (1.0f / 256.0f);
        vt_g[t * GV + tid] = vocf(sj) - It * interp33(zrow, sj);
    }
}

// ---------------------------------------------------------------------------
// Phase B: whole filter, 1 block, 128 threads (2 waves, 4 particles/lane),
// 2 light barriers/step, marker-based resample, V-table GV=257.
// ---------------------------------------------------------------------------
__global__ __launch_bounds__(128, 1) void k_seq(
    const float* __restrict__ vt_g, const float* __restrict__ soc_init,
    const float* __restrict__ current, const float* __restrict__ vmeas,
    const float* __restrict__ u, const float* __restrict__ noise,
    float* __restrict__ vbuf, float* __restrict__ sbuf, float* __restrict__ out)
{
    const int tid = threadIdx.x;
    const int lane = tid & 63;
    const int wv = tid >> 6;          // 0 or 1

    __shared__ __align__(16) float vt[TS * GV];     // 131.6 KB
    __shared__ __align__(16) float socs[2][NP];
    __shared__ __align__(16) int marker[NP];
    __shared__ float cur_s[TS], vm_s[TS], u_s[TS];
    __shared__ __align__(16) float2 redMT[2];

    // ---- preamble: stream tables in ----
    for (int i4 = tid; i4 < (TS * GV) / 4; i4 += 128)
        *(float4*)&vt[i4 * 4] = *(const float4*)&vt_g[i4 * 4];
    { int r = TS * GV - (TS * GV / 4) * 4; (void)r; }   // TS*GV=32896 divisible by 4
    cur_s[tid] = current[tid]; vm_s[tid] = vmeas[tid]; u_s[tid] = u[tid];
    *(int4*)&marker[4 * tid] = make_int4(0, 0, 0, 0);
    __syncthreads();

    float4 si4 = *(const float4*)&soc_init[4 * tid];
    float soc0 = si4.x, soc1 = si4.y, soc2 = si4.z, soc3 = si4.w;
    float Iprev = cur_s[0];
    float V0 = interp257(&vt[0], soc0);
    float V1 = interp257(&vt[0], soc1);
    float V2 = interp257(&vt[0], soc2);
    float V3 = interp257(&vt[0], soc3);
    float loss_acc = 0.f;
    const float LOG_NU = logf(19.947114020071635f);
    const float LOG_N = logf(512.f);
    float4 nz = *(const float4*)&noise[4 * tid];

    for (int t = 0; t < TS; ++t) {
        int tn = (t + 1 < TS) ? t + 1 : t;
        float4 nz_next = *(const float4*)&noise[tn * 512 + 4 * tid];  // in flight

        // ---- A: propagate 4 particles, V, logW, wave max + quad scan ----
        soc0 = soc0 - Iprev * V0 * E_INV + F_STDc * nz.x;
        soc1 = soc1 - Iprev * V1 * E_INV + F_STDc * nz.y;
        soc2 = soc2 - Iprev * V2 * E_INV + F_STDc * nz.z;
        soc3 = soc3 - Iprev * V3 * E_INV + F_STDc * nz.w;
        soc0 = soc0 > 1.f ? 1.f : (soc0 < 0.f ? 1e-10f : soc0);
        soc1 = soc1 > 1.f ? 1.f : (soc1 < 0.f ? 1e-10f : soc1);
        soc2 = soc2 > 1.f ? 1.f : (soc2 < 0.f ? 1e-10f : soc2);
        soc3 = soc3 > 1.f ? 1.f : (soc3 < 0.f ? 1e-10f : soc3);
        *(float4*)&socs[t & 1][4 * tid] = make_float4(soc0, soc1, soc2, soc3);

        const float* vr = &vt[t * GV];
        V0 = interp257(vr, soc0);
        V1 = interp257(vr, soc1);
        V2 = interp257(vr, soc2);
        V3 = interp257(vr, soc3);
        *(float4*)&vbuf[t * 512 + 4 * tid] = make_float4(V0, V1, V2, V3);
        float vm = vm_s[t];
        float d0 = (V0 - vm) * (1.f / G_STDc);
        float d1 = (V1 - vm) * (1.f / G_STDc);
        float d2 = (V2 - vm) * (1.f / G_STDc);
        float d3 = (V3 - vm) * (1.f / G_STDc);
        float lw0 = LOG_NU - 0.5f * d0 * d0;
        float lw1 = LOG_NU - 0.5f * d1 * d1;
        float lw2 = LOG_NU - 0.5f * d2 * d2;
        float lw3 = LOG_NU - 0.5f * d3 * d3;

        float m = wave_max_f(fmaxf(fmaxf(lw0, lw1), fmaxf(lw2, lw3)));
        float e0 = __expf(lw0 - m);
        float e1 = __expf(lw1 - m);
        float e2 = __expf(lw2 - m);
        float e3 = __expf(lw3 - m);
        float c0 = e0;
        float c1 = c0 + e1;
        float c2 = c1 + e2;
        float c3 = c2 + e3;
        float tot = c3;
        float incl = wave_scan_add(tot, lane);
        if (lane == 63) redMT[wv] = make_float2(m, incl);
        LBAR();                                            // barrier 1

        // ---- B: 2-wave combine via one b128 read ----
        float4 rr = *(float4*)&redMT[0];   // (m0, T0, m1, T1)
        float M = fmaxf(rr.x, rr.z);
        float fw0 = __expf(rr.x - M);
        float fw1 = __expf(rr.z - M);
        float t0 = rr.y * fw0;
        float t1 = rr.w * fw1;
        float S = t0 + t1;
        float off = wv ? t0 : 0.f;
        float fw_own = wv ? fw1 : fw0;
        loss_acc += M + __logf(S) - LOG_N;

        float base = incl - tot;
        float ut = u_s[t];
        float C0 = 512.f * ((off + (base + c0) * fw_own) / S);
        float C1 = 512.f * ((off + (base + c1) * fw_own) / S);
        float C2 = 512.f * ((off + (base + c2) * fw_own) / S);
        float C3 = 512.f * ((off + (base + c3) * fw_own) / S);
        int hi0 = count_le(C0, ut);
        int hi1 = count_le(C1, ut);
        int hi2 = count_le(C2, ut);
        int hi3 = count_le(C3, ut);
        int p4 = 4 * tid;
        if (hi0 < 512) atomicMax(&marker[hi0], (t << 10) | (p4 + 1));
        if (hi1 < 512) atomicMax(&marker[hi1], (t << 10) | (p4 + 2));
        if (hi2 < 512) atomicMax(&marker[hi2], (t << 10) | (p4 + 3));
        if (hi3 < 512) atomicMax(&marker[hi3], (t << 10) | (p4 + 4));
        LBAR();                                            // barrier 2

        // ---- C: owner via quad scanmax of markers, gather, stores ----
        int4 mk = *(int4*)&marker[4 * tid];
        int4 oth = *(int4*)&marker[4 * lane];   // wave-0 region (slots 0..255)
        int pm = 0;
        if (wv) pm = wave_max_i(max(max(oth.x, oth.y), max(oth.z, oth.w)));
        int lm = max(max(mk.x, mk.y), max(mk.z, mk.w));
        int psx = wave_scanmax_i(lm, lane);
        int up = dpp_shr<1>(psx);
        int r15 = __builtin_amdgcn_readlane(psx, 15);
        int r31 = __builtin_amdgcn_readlane(psx, 31);
        int r47 = __builtin_amdgcn_readlane(psx, 47);
        if (lane == 16) up = r15;
        if (lane == 32) up = r31;
        if (lane == 48) up = r47;   // lane 0: 0 via bound_ctrl
        int excl = max(up, pm);
        int tag0 = max(excl, mk.x);
        int tag1 = max(tag0, mk.y);
        int tag2 = max(tag1, mk.z);
        int tag3 = max(tag2, mk.w);
        int o0 = ((tag0 >> 10) == t) ? (tag0 & 1023) : 0;
        int o1 = ((tag1 >> 10) == t) ? (tag1 & 1023) : 0;
        int o2 = ((tag2 >> 10) == t) ? (tag2 & 1023) : 0;
        int o3 = ((tag3 >> 10) == t) ? (tag3 & 1023) : 0;
        o0 = o0 > 511 ? 511 : o0;
        o1 = o1 > 511 ? 511 : o1;
        o2 = o2 > 511 ? 511 : o2;
        o3 = o3 > 511 ? 511 : o3;
        const float* sflat = &socs[t & 1][0];
        float sr0 = sflat[o0];
        float sr1 = sflat[o1];
        float sr2 = sflat[o2];
        float sr3 = sflat[o3];
        *(float4*)&sbuf[t * 512 + 4 * tid] = make_float4(sr0, sr1, sr2, sr3);

        soc0 = sr0; soc1 = sr1; soc2 = sr2; soc3 = sr3;
        Iprev = cur_s[t];
        nz = nz_next;
    }
    if (tid == 0) out[0] = loss_acc;
}

// ---------------------------------------------------------------------------
// Phase C: transpose time-major [128][512] -> particle-major [512][128]
// ---------------------------------------------------------------------------
__global__ __launch_bounds__(256) void k_fin(
    const float* __restrict__ vbuf, const float* __restrict__ sbuf,
    float* __restrict__ out)
{
    __shared__ float tile[32][33];
    int tz = blockIdx.z;
    int t0 = blockIdx.x * 32;
    int i0 = blockIdx.y * 32;
    const float* src = tz ? sbuf : vbuf;
    float* dst = out + 1 + tz * (NP * TS);
    int tx = threadIdx.x & 31, ty = threadIdx.x >> 5;
    #pragma unroll
    for (int m2 = 0; m2 < 4; ++m2)
        tile[ty + 8 * m2][tx] = src[(t0 + ty + 8 * m2) * 512 + i0 + tx];
    __syncthreads();
    #pragma unroll
    for (int m2 = 0; m2 < 4; ++m2)
        dst[(i0 + ty + 8 * m2) * 128 + t0 + tx] = tile[tx][ty + 8 * m2];
}

extern "C" void kernel_launch(void* const* d_in, const int* in_sizes, int n_in,
                              void* d_out, int out_size, void* d_ws, size_t ws_size,
                              hipStream_t stream)
{
    const float* soc_init = (const float*)d_in[0];
    const float* current  = (const float*)d_in[1];
    const float* vmeas    = (const float*)d_in[2];
    const float* noise    = (const float*)d_in[3];
    const float* u        = (const float*)d_in[4];
    const float* w1 = (const float*)d_in[5];
    const float* b1 = (const float*)d_in[6];
    const float* w2 = (const float*)d_in[7];
    const float* b2 = (const float*)d_in[8];
    const float* w3 = (const float*)d_in[9];
    const float* b3 = (const float*)d_in[10];
    float* out = (float*)d_out;
    float* ws  = (float*)d_ws;

    float* zpart = ws;                         // 2*TAB2D = 2178 floats
    float* vt_g  = ws + 2180;                  // 32896 floats (16B aligned)
    float* vbuf  = vt_g + TS * GV;             // 65536 floats
    float* sbuf  = vbuf + NP * TS;             // 65536 floats

    k_tab<<<138, 256, 0, stream>>>(w1, b1, w2, b2, w3, zpart);
    k_pre<<<128, 320, 0, stream>>>(zpart, current, b3, vt_g);
    k_seq<<<1, 128, 0, stream>>>(vt_g, soc_init, current, vmeas, u, noise,
                                 vbuf, sbuf, out);
    k_fin<<<dim3(4, 16, 2), 256, 0, stream>>>(vbuf, sbuf, out);
}